// Round 8
// baseline (76.766 us; speedup 1.0000x reference)
//
#include <hip/hip_runtime.h>

// SGNN projection, round 8: cnt4 compaction + 8 waves/SIMD occupancy (register-lean).
//
// Math (M = 2^31-1 Mersenne, HALF = 2^30-1):
//   centered(v) = ((v + HALF) mod M) - HALF  ->  p2 = sig*seed + HALF (one v_mad_u64_u32).
//   Fold: s = (p2>>31) + (p2 & M) <= 2^32-4 < 2M ALWAYS (sig,seed <= 2^31-2), so
//   residue = s - M*[s>=M] exactly. centered partial = sum(s) - M*q - n*HALF, exact int64.
//   Pad-zero slots (sig=0) give s = HALF exactly, removed by the n*HALF term.
//
// R8 hypothesis: residual ~2x over issue floor is latency exposure at 4 waves/SIMD
// (R6/R7 regressed launch_bounds to (256,4); R3 at (256,8) measured fewer cyc/elem).
// So: (256,8) + minimal live registers (no prefetch pipeline, step-8 loop, 2 chains).

#define M31    2147483647u   // 2^31 - 1
#define HALF_B 1073741823u   // 2^30 - 1

__global__ __launch_bounds__(64) void sgnn_prep_kernel(
    const int* __restrict__ sig,    // [3, B, 128]
    const int* __restrict__ mask,   // [3, B, 128]
    unsigned* __restrict__ msig,    // [3, B, 128] compacted, zero-padded to cnt4
    float* __restrict__ invc,       // [3, B] = 1/(max(cnt,1)*HALF)
    unsigned* __restrict__ cnt4)    // [3, B] = ceil(cnt/4)*4
{
    const int row = blockIdx.x;          // p*nbatch + b
    const int t   = threadIdx.x;         // one wave
    const int g0  = row * 128 + t;
    const int g1  = g0 + 64;
    const int mk0 = mask[g0], mk1 = mask[g1];
    const unsigned v0 = (unsigned)sig[g0], v1 = (unsigned)sig[g1];

    const unsigned long long b0 = __ballot(mk0 != 0);
    const unsigned long long b1 = __ballot(mk1 != 0);
    const unsigned long long lt = (1ULL << t) - 1ULL;
    const int c0   = __popcll(b0);
    const int cnt  = c0 + __popcll(b1);
    const int pos0 = __popcll(b0 & lt);
    const int pos1 = c0 + __popcll(b1 & lt);

    const unsigned base = (unsigned)row * 128u;
    if (mk0) msig[base + pos0] = v0;
    if (mk1) msig[base + pos1] = v1;

    const int c4 = (cnt + 3) & ~3;
    if (cnt + t < c4) msig[base + cnt + t] = 0u;   // zero-pad (<=3 slots)

    if (t == 0) {
        int c = (cnt < 1) ? 1 : cnt;
        invc[row] = 1.0f / ((float)c * 1073741823.0f);
        cnt4[row] = (unsigned)c4;
    }
}

__device__ __forceinline__ void acc_elem(unsigned v, unsigned seed,
                                         unsigned long long& sum, unsigned& q) {
    const unsigned long long p2 =
        (unsigned long long)v * (unsigned long long)seed + (unsigned long long)HALF_B;
    const unsigned lo = (unsigned)p2;
    const unsigned hi = (unsigned)(p2 >> 32);
    const unsigned s  = __builtin_amdgcn_alignbit(hi, lo, 31) + (lo & 0x7FFFFFFFu);
    q   += (s >= M31);
    sum += s;
}

__device__ __forceinline__ void acc4(uint4 a, unsigned seed,
                                     unsigned long long& s0, unsigned long long& s1,
                                     unsigned& q0, unsigned& q1) {
    acc_elem(a.x, seed, s0, q0); acc_elem(a.y, seed, s1, q1);
    acc_elem(a.z, seed, s0, q0); acc_elem(a.w, seed, s1, q1);
}

__global__ __launch_bounds__(256, 8) void sgnn_main_kernel(
    const unsigned* __restrict__ msig,  // [3, B, 128] compacted
    const float* __restrict__ invc,     // [3, B]
    const unsigned* __restrict__ cnt4,  // [3, B]
    const int* __restrict__ seeds,      // [672]
    float* __restrict__ out,            // [B, 672] == flat[t]
    int nbatch)
{
    const unsigned t = blockIdx.x * 256u + threadIdx.x;  // [0, nbatch*672)
    // b = floor(t/672) = floor((t>>5)/21), exact for t < 2^21 via magic 99865 = ceil(2^21/21)
    const unsigned x = t >> 5;
    const unsigned b = (x * 99865u) >> 21;
    const unsigned h = t - 672u * b;
    const int p = (h < 112u) ? 0 : (h < 336u) ? 1 : 2;

    const unsigned row = (unsigned)(p * nbatch) + b;
    const unsigned* __restrict__ rp = msig + row * 128u;
    const unsigned seed = (unsigned)seeds[h];
    const unsigned n = cnt4[row];        // multiple of 4, may be 0

    unsigned long long sum0 = 0, sum1 = 0;  // s < 2^32 each; <=128 elems < 2^39, exact
    unsigned q0 = 0, q1 = 0;

    unsigned mm = 0;
    const unsigned n8 = n & ~7u;
    for (; mm < n8; mm += 8) {           // register-lean: 2 loads in flight
        const uint4 a = *(const uint4*)(rp + mm);
        const uint4 c = *(const uint4*)(rp + mm + 4);
        acc4(a, seed, sum0, sum1, q0, q1);
        acc4(c, seed, sum0, sum1, q0, q1);
    }
    if (mm < n) {                        // single step-4 tail
        const uint4 a = *(const uint4*)(rp + mm);
        acc4(a, seed, sum0, sum1, q0, q1);
    }

    const long long centered = (long long)(sum0 + sum1)
                             - (long long)(q0 + q1) * 2147483647LL
                             - (long long)n * 1073741823LL;
    out[t] = (float)centered * invc[row];
}

extern "C" void kernel_launch(void* const* d_in, const int* in_sizes, int n_in,
                              void* d_out, int out_size, void* d_ws, size_t ws_size,
                              hipStream_t stream) {
    const int* sig   = (const int*)d_in[0];
    const int* mask  = (const int*)d_in[1];
    const int* seeds = (const int*)d_in[2];
    float* out = (float*)d_out;

    const int nbatch = in_sizes[0] / (3 * 128);         // 1024
    const int nrows  = 3 * nbatch;                      // 3072
    unsigned* msig = (unsigned*)d_ws;                                    // nrows*128 u32
    float*    invc = (float*)((char*)d_ws + (size_t)nrows * 128 * 4);    // nrows f32
    unsigned* c4   = (unsigned*)((char*)d_ws + (size_t)nrows * 132 * 4); // nrows u32

    sgnn_prep_kernel<<<dim3(nrows), dim3(64), 0, stream>>>(sig, mask, msig, invc, c4);
    const int total = nbatch * 672;                     // 688128 = 2688 * 256 exactly
    sgnn_main_kernel<<<dim3(total / 256), dim3(256), 0, stream>>>(msig, invc, c4, seeds, out, nbatch);
}